// Round 6
// baseline (11075.824 us; speedup 1.0000x reference)
//
#include <hip/hip_runtime.h>
#include <hip/hip_bf16.h>
#include <stdint.h>

// RNN: h_t = relu(xs_t @ W_ih^T + h_{t-1} @ W_hh^T); ys = (h_seq @ W_out^T) -> [B,T,O]
// R6: flagless self-validating dataflow.
//  - hseq holds ONLY h (bf16, sliced layout), zeroed per call via hipMemsetAsync.
//  - Producers store h with every bf16 sign bit SET (h>=0, sign is a free tag) via
//    write-through sc0sc1 8B stores. No drain, no flags.
//  - Consumers use CACHEABLE 16B loads (L2-shared across the XCD); freshness = all 32
//    sign bits set; on failure: agent acquire fence (buffer_inv) + retry.
//  - P = xs@Wih^T is computed on the fly inside the recurrence (4 MFMAs/wave from a
//    32KB Wih LDS slice, xs prefetched one step ahead) -> phase-1 GEMM deleted.
//  - Phase 3 masks the tag bits off A.

#define TT 512
#define BB 64
#define NIN 1024
#define NH 2048
#define NOUT 1024

typedef __attribute__((ext_vector_type(8))) short bf8;
typedef __attribute__((ext_vector_type(4))) float f4;
typedef __attribute__((ext_vector_type(4))) unsigned int u4;

static __device__ __forceinline__ unsigned short f2bf(float f) {
  __hip_bfloat16 h = __float2bfloat16(f);
  return __builtin_bit_cast(unsigned short, h);
}
static __device__ __forceinline__ float bf2f(unsigned short v) {
  return __bfloat162float(__builtin_bit_cast(__hip_bfloat16, v));
}
static __device__ __forceinline__ u4 pack8(const float* f) {
  u4 r;
#pragma unroll
  for (int i = 0; i < 4; ++i) {
    unsigned lo = f2bf(f[2 * i]);
    unsigned hi = f2bf(f[2 * i + 1]);
    r[i] = lo | (hi << 16);
  }
  return r;
}

// sliced-layout element index for (m-row, k/j-col): h[t=m>>6][col>>4][m&63][col&15]
static __device__ __forceinline__ size_t sl_idx(int m, int col) {
  return (((size_t)(m >> 6) * 128 + (col >> 4)) << 10) + (size_t)(m & 63) * 16 + (col & 15);
}

// ---------------- generic C[M,N] = A[M,K] * B[N,K]^T (bf16 MFMA) ----------------
// ABF: A is bf16 in sliced layout with tag sign bits (masked off here). B is f32 weights.
// TRANS: store f32 out[b][t][n]; else store bf16 into sliced layout.
template <bool ABF, bool TRANS>
__global__ void gemm_bt(const void* __restrict__ Av, const float* __restrict__ Bw,
                        void* __restrict__ Cv, int M, int N, int K) {
  constexpr int BM = 128, BN = 128, BK = 32;
  __shared__ u4 As[BM * 4];
  __shared__ u4 Bs[BN * 4];
  const int nt = N / BN;
  const int mi = (int)blockIdx.x / nt;
  const int ni = (int)blockIdx.x % nt;
  const int m0 = mi * BM, n0 = ni * BN;
  const int t = threadIdx.x;
  const int l = t & 63, w = t >> 6, wr = w >> 1, wc = w & 1;
  const int lr = l & 15, lq = l >> 4;

  f4 acc[4][4] = {};

  const int srow = t >> 1;
  const int sc0 = (t & 1) * 2;
  const u4 msk = {0x7fff7fffu, 0x7fff7fffu, 0x7fff7fffu, 0x7fff7fffu};

  for (int kt = 0; kt < K; kt += BK) {
    if (ABF) {
      const unsigned short* A = (const unsigned short*)Av;
#pragma unroll
      for (int cc = 0; cc < 2; ++cc) {
        int c = sc0 + cc;
        u4 v = *(const u4*)(A + sl_idx(m0 + srow, kt + c * 8));
        v &= msk;  // strip tag sign bits
        As[srow * 4 + (c ^ ((srow ^ (srow >> 2)) & 3))] = v;
      }
    } else {
      const float* A = (const float*)Av;
#pragma unroll
      for (int cc = 0; cc < 2; ++cc) {
        int c = sc0 + cc;
        const float* p = A + (size_t)(m0 + srow) * K + kt + c * 8;
        float4 v0 = *(const float4*)p;
        float4 v1 = *(const float4*)(p + 4);
        float f[8] = {v0.x, v0.y, v0.z, v0.w, v1.x, v1.y, v1.z, v1.w};
        As[srow * 4 + (c ^ ((srow ^ (srow >> 2)) & 3))] = pack8(f);
      }
    }
#pragma unroll
    for (int cc = 0; cc < 2; ++cc) {
      int c = sc0 + cc;
      const float* p = Bw + (size_t)(n0 + srow) * K + kt + c * 8;
      float4 v0 = *(const float4*)p;
      float4 v1 = *(const float4*)(p + 4);
      float f[8] = {v0.x, v0.y, v0.z, v0.w, v1.x, v1.y, v1.z, v1.w};
      Bs[srow * 4 + (c ^ ((srow ^ (srow >> 2)) & 3))] = pack8(f);
    }
    __syncthreads();

    bf8 a[4], b[4];
#pragma unroll
    for (int i = 0; i < 4; ++i) {
      int ra = wr * 64 + i * 16 + lr;
      a[i] = __builtin_bit_cast(bf8, As[ra * 4 + (lq ^ ((ra ^ (ra >> 2)) & 3))]);
      int rb = wc * 64 + i * 16 + lr;
      b[i] = __builtin_bit_cast(bf8, Bs[rb * 4 + (lq ^ ((rb ^ (rb >> 2)) & 3))]);
    }
#pragma unroll
    for (int i = 0; i < 4; ++i)
#pragma unroll
      for (int j = 0; j < 4; ++j)
        acc[i][j] = __builtin_amdgcn_mfma_f32_16x16x32_bf16(a[i], b[j], acc[i][j], 0, 0, 0);
    __syncthreads();
  }

  if (TRANS) {
    float* C = (float*)Cv;
#pragma unroll
    for (int i = 0; i < 4; ++i)
#pragma unroll
      for (int j = 0; j < 4; ++j)
#pragma unroll
        for (int r = 0; r < 4; ++r) {
          int m = m0 + wr * 64 + i * 16 + lq * 4 + r;
          int n = n0 + wc * 64 + j * 16 + lr;
          C[(size_t)(m & 63) * (TT * NOUT) + (size_t)(m >> 6) * NOUT + n] = acc[i][j][r];
        }
  } else {
    unsigned short* C = (unsigned short*)Cv;
#pragma unroll
    for (int i = 0; i < 4; ++i)
#pragma unroll
      for (int j = 0; j < 4; ++j)
#pragma unroll
        for (int r = 0; r < 4; ++r) {
          int m = m0 + wr * 64 + i * 16 + lq * 4 + r;
          int n = n0 + wc * 64 + j * 16 + lr;
          C[sl_idx(m, n)] = f2bf(acc[i][j][r]);
        }
  }
}

// ---------------- persistent fused recurrence kernel (flagless) -------------------
// 256 blocks: blockIdx.x = bh*128 + jb. Block produces h slice (rows bh*32..+32, cols
// jb*16..+16) each step. 16 waves = bg(2) x kg(8). Per wave per step: 4 Wih MFMAs over
// prefetched xs frags (k-range kg*128..+128 of 1024) + 8 Whh MFMAs over retry-verified
// h_{t-1} frags (k-range kg*256..+256 of 2048). Partials -> red LDS; waves 0/1 reduce,
// relu, tag sign bits, write-through-store. ts=0 is the P-only step (h_0 = relu(P_0)).
__global__ __launch_bounds__(1024, 4) void rnn_recur(unsigned short* __restrict__ hseq,
                                                     const float* __restrict__ xs,
                                                     const float* __restrict__ Whh,
                                                     const float* __restrict__ Wih) {
  __shared__ u4 Wlh[16 * 256];         // 64 KiB: Whh [j_local][k-chunk of 8], chunk ^ (j&7)
  __shared__ u4 Wli[16 * 128];         // 32 KiB: Wih same scheme (128 chunks)
  __shared__ float red[2][8][32][20];  // 40 KiB: [buf][kg][local row][j 16 pad 20]
  const int t = threadIdx.x;
  const int jb = (int)blockIdx.x & 127;
  const int bh = (int)blockIdx.x >> 7;
  const int j0 = jb * 16;

  // one-time: W_hh and W_ih j-slices -> swizzled LDS (f32 -> bf16)
  {
    const int jl = t >> 6;
    const int c0 = (t & 63) * 4;
#pragma unroll
    for (int c = 0; c < 4; ++c) {
      int cc = c0 + c;
      const float* p = Whh + (size_t)(j0 + jl) * NH + cc * 8;
      float4 v0 = *(const float4*)p;
      float4 v1 = *(const float4*)(p + 4);
      float f[8] = {v0.x, v0.y, v0.z, v0.w, v1.x, v1.y, v1.z, v1.w};
      Wlh[jl * 256 + (cc ^ (jl & 7))] = pack8(f);
    }
    const int i0 = (t & 63) * 2;
#pragma unroll
    for (int c = 0; c < 2; ++c) {
      int cc = i0 + c;
      const float* p = Wih + (size_t)(j0 + jl) * NIN + cc * 8;
      float4 v0 = *(const float4*)p;
      float4 v1 = *(const float4*)(p + 4);
      float f[8] = {v0.x, v0.y, v0.z, v0.w, v1.x, v1.y, v1.z, v1.w};
      Wli[jl * 128 + (cc ^ (jl & 7))] = pack8(f);
    }
  }

  const int l = t & 63, w = t >> 6;
  const int lr = l & 15, lq = l >> 4;
  const int bg = w & 1, kg = w >> 1;
  const int row = bh * 32 + bg * 16 + lr;  // b-row of this lane's A fragments

  // writer-wave lane roles (waves 0/1): 64 lanes = 16 local rows x 4 j-quarters
  const int wrowL = bg * 16 + (l >> 2);
  const int wjq = l & 3;
  const size_t woff = (size_t)(bh * 32 + wrowL) * 16 + wjq * 4;

  const u4 msk = {0x7fff7fffu, 0x7fff7fffu, 0x7fff7fffu, 0x7fff7fffu};

  // xs fragment prefetch (f32 -> bf16): k = kg*128 + lq*8 + u*32, u=0..3
  bf8 xf[4];
  auto load_xs = [&](int tt) {
    const float* xp = xs + ((size_t)tt * BB + row) * NIN + kg * 128 + lq * 8;
#pragma unroll
    for (int u = 0; u < 4; ++u) {
      float4 v0 = *(const float4*)(xp + u * 32);
      float4 v1 = *(const float4*)(xp + u * 32 + 4);
      float f[8] = {v0.x, v0.y, v0.z, v0.w, v1.x, v1.y, v1.z, v1.w};
      xf[u] = __builtin_bit_cast(bf8, pack8(f));
    }
  };
  load_xs(0);

  __syncthreads();  // LDS weights ready

  for (int ts = 0; ts < TT; ++ts) {
    f4 acc0 = {}, acc1 = {};

    // ---- P contribution: 4 MFMAs over prefetched xs frags ----
#pragma unroll
    for (int u = 0; u < 4; ++u) {
      int c = kg * 16 + u * 4 + lq;
      bf8 bfr = __builtin_bit_cast(bf8, Wli[lr * 128 + (c ^ (lr & 7))]);
      if (u & 1)
        acc1 = __builtin_amdgcn_mfma_f32_16x16x32_bf16(xf[u], bfr, acc1, 0, 0, 0);
      else
        acc0 = __builtin_amdgcn_mfma_f32_16x16x32_bf16(xf[u], bfr, acc0, 0, 0, 0);
    }

    // ---- recurrent contribution: retry-verified cacheable loads of h_{ts-1} ----
    if (ts > 0) {
      const size_t tb = (size_t)(ts - 1) * 128;
      const size_t rowoff = (size_t)row * 16 + (lq & 1) * 8;
      const size_t sbase = tb + kg * 16 + (lq >> 1);
      unsigned long long ad[8];
#pragma unroll
      for (int u = 0; u < 8; ++u)
        ad[u] = (unsigned long long)(uintptr_t)(hseq + (((sbase + 2 * u) << 10) + rowoff));
      u4 av[8];
      long spins = 0;
      for (;;) {
        asm volatile(
            "global_load_dwordx4 %0, %8, off\n\t"
            "global_load_dwordx4 %1, %9, off\n\t"
            "global_load_dwordx4 %2, %10, off\n\t"
            "global_load_dwordx4 %3, %11, off\n\t"
            "global_load_dwordx4 %4, %12, off\n\t"
            "global_load_dwordx4 %5, %13, off\n\t"
            "global_load_dwordx4 %6, %14, off\n\t"
            "global_load_dwordx4 %7, %15, off\n\t"
            "s_waitcnt vmcnt(0)"
            : "=&v"(av[0]), "=&v"(av[1]), "=&v"(av[2]), "=&v"(av[3]),
              "=&v"(av[4]), "=&v"(av[5]), "=&v"(av[6]), "=&v"(av[7])
            : "v"(ad[0]), "v"(ad[1]), "v"(ad[2]), "v"(ad[3]),
              "v"(ad[4]), "v"(ad[5]), "v"(ad[6]), "v"(ad[7])
            : "memory");
        unsigned m = 0xffffffffu;
#pragma unroll
        for (int u = 0; u < 8; ++u)
#pragma unroll
          for (int d = 0; d < 4; ++d) m &= av[u][d];
        bool ok = (m & 0x80008000u) == 0x80008000u;  // all 32 sign bits set -> fresh h
        if (__ballot(ok) == ~0ull) break;
        __builtin_amdgcn_fence(__ATOMIC_ACQUIRE, "agent");  // invalidate stale L1/L2 lines
        __builtin_amdgcn_s_sleep(1);
        if (++spins > (1L << 20)) break;  // hang safety; never hit when logic is correct
      }
#pragma unroll
      for (int u = 0; u < 8; ++u) {
        u4 v = av[u] & msk;  // strip tag signs
        bf8 af = __builtin_bit_cast(bf8, v);
        int c = kg * 32 + u * 4 + lq;
        bf8 bfr = __builtin_bit_cast(bf8, Wlh[lr * 256 + (c ^ (lr & 7))]);
        if (u & 1)
          acc1 = __builtin_amdgcn_mfma_f32_16x16x32_bf16(af, bfr, acc1, 0, 0, 0);
        else
          acc0 = __builtin_amdgcn_mfma_f32_16x16x32_bf16(af, bfr, acc0, 0, 0, 0);
      }
    }

    // prefetch next xs (plain cacheable; completes under epilogue/next-step wait)
    if (ts + 1 < TT) load_xs(ts + 1);

    f4 a2 = acc0 + acc1;
    const int buf = ts & 1;
#pragma unroll
    for (int r = 0; r < 4; ++r) red[buf][kg][bg * 16 + lq * 4 + r][lr] = a2[r];
    __syncthreads();

    if (w < 2) {
      f4 s = {};
#pragma unroll
      for (int q = 0; q < 8; ++q) s += *(const f4*)&red[buf][q][wrowL][wjq * 4];
      unsigned short h0 = (s[0] > 0.f) ? f2bf(s[0]) : (unsigned short)0;
      unsigned short h1 = (s[1] > 0.f) ? f2bf(s[1]) : (unsigned short)0;
      unsigned short h2 = (s[2] > 0.f) ? f2bf(s[2]) : (unsigned short)0;
      unsigned short h3 = (s[3] > 0.f) ? f2bf(s[3]) : (unsigned short)0;
      unsigned long long hv = (unsigned long long)h0 | ((unsigned long long)h1 << 16) |
                              ((unsigned long long)h2 << 32) | ((unsigned long long)h3 << 48);
      hv |= 0x8000800080008000ull;  // tag: sign bit of every bf16 set
      size_t eo = (((size_t)ts * 128 + jb) << 10) + woff;
      __hip_atomic_store((unsigned long long*)(hseq + eo), hv, __ATOMIC_RELAXED,
                         __HIP_MEMORY_SCOPE_AGENT);  // write-through to LLC; no drain needed
    }
  }
}

extern "C" void kernel_launch(void* const* d_in, const int* in_sizes, int n_in,
                              void* d_out, int out_size, void* d_ws, size_t ws_size,
                              hipStream_t stream) {
  const float* xs = (const float*)d_in[0];
  const float* Wih = (const float*)d_in[1];
  const float* Whh = (const float*)d_in[2];
  const float* Wout = (const float*)d_in[3];

  unsigned short* hseq = (unsigned short*)d_ws;  // sliced [TT][128][64][16] bf16 = 128 MiB

  // zero hseq: "not ready" state (sign bits clear). Required every call (tag protocol).
  hipMemsetAsync(d_ws, 0, (size_t)TT * BB * NH * 2, stream);

  // fused phase 1+2: recurrence with on-the-fly P
  rnn_recur<<<256, 1024, 0, stream>>>(hseq, xs, Whh, Wih);

  // phase 3: out[b][t][o] = h_seq @ W_out^T (strips tag bits)
  gemm_bt<true, true><<<(TT * BB / 128) * (NOUT / 128), 256, 0, stream>>>(
      (const void*)hseq, Wout, d_out, TT * BB, NOUT, NH);
}

// Round 7
// 4152.508 us; speedup vs baseline: 2.6673x; 2.6673x over previous
//
#include <hip/hip_runtime.h>
#include <hip/hip_bf16.h>
#include <stdint.h>

// RNN: h_t = relu(xs_t @ W_ih^T + h_{t-1} @ W_hh^T); ys = (h_seq @ W_out^T) -> [B,T,O]
// R7 = R5 + cacheable consumer h-loads (L2-shared across each XCD; IC amplification
// 32MB/step -> ~2-4MB/step) enabled by making the ONLY pre-write cacheable toucher of
// hseq (the own-block P-prefetch) a bypass load. No fences anywhere. Safety argument:
// a consumer L2 line for h slice (t-1,s) can only have been filled by a post-flag
// reader (fresh) -- P stores from phase 1 are flushed at the kernel boundary, h stores
// are write-through (no dirty allocate), P-prefetch no longer cache-fills.

#define TT 512
#define BB 64
#define NIN 1024
#define NH 2048
#define NOUT 1024

typedef __attribute__((ext_vector_type(8))) short bf8;
typedef __attribute__((ext_vector_type(4))) float f4;
typedef __attribute__((ext_vector_type(4))) unsigned int u4;

static __device__ __forceinline__ unsigned short f2bf(float f) {
  __hip_bfloat16 h = __float2bfloat16(f);
  return __builtin_bit_cast(unsigned short, h);
}
static __device__ __forceinline__ float bf2f(unsigned short v) {
  return __bfloat162float(__builtin_bit_cast(__hip_bfloat16, v));
}
static __device__ __forceinline__ u4 pack8(const float* f) {
  u4 r;
#pragma unroll
  for (int i = 0; i < 4; ++i) {
    unsigned lo = f2bf(f[2 * i]);
    unsigned hi = f2bf(f[2 * i + 1]);
    r[i] = lo | (hi << 16);
  }
  return r;
}

// sliced-layout element index for (m-row, k/j-col): h[t=m>>6][col>>4][m&63][col&15]
static __device__ __forceinline__ size_t sl_idx(int m, int col) {
  return (((size_t)(m >> 6) * 128 + (col >> 4)) << 10) + (size_t)(m & 63) * 16 + (col & 15);
}

// ---------------- generic C[M,N] = A[M,K] * B[N,K]^T (bf16 MFMA) ----------------
template <bool ABF, bool TRANS>
__global__ void gemm_bt(const void* __restrict__ Av, const float* __restrict__ Bw,
                        void* __restrict__ Cv, int M, int N, int K) {
  constexpr int BM = 128, BN = 128, BK = 32;
  __shared__ u4 As[BM * 4];
  __shared__ u4 Bs[BN * 4];
  const int nt = N / BN;
  const int mi = (int)blockIdx.x / nt;
  const int ni = (int)blockIdx.x % nt;
  const int m0 = mi * BM, n0 = ni * BN;
  const int t = threadIdx.x;
  const int l = t & 63, w = t >> 6, wr = w >> 1, wc = w & 1;
  const int lr = l & 15, lq = l >> 4;

  f4 acc[4][4] = {};

  const int srow = t >> 1;
  const int sc0 = (t & 1) * 2;

  for (int kt = 0; kt < K; kt += BK) {
    if (ABF) {
      const unsigned short* A = (const unsigned short*)Av;
#pragma unroll
      for (int cc = 0; cc < 2; ++cc) {
        int c = sc0 + cc;
        u4 v = *(const u4*)(A + sl_idx(m0 + srow, kt + c * 8));
        As[srow * 4 + (c ^ ((srow ^ (srow >> 2)) & 3))] = v;
      }
    } else {
      const float* A = (const float*)Av;
#pragma unroll
      for (int cc = 0; cc < 2; ++cc) {
        int c = sc0 + cc;
        const float* p = A + (size_t)(m0 + srow) * K + kt + c * 8;
        float4 v0 = *(const float4*)p;
        float4 v1 = *(const float4*)(p + 4);
        float f[8] = {v0.x, v0.y, v0.z, v0.w, v1.x, v1.y, v1.z, v1.w};
        As[srow * 4 + (c ^ ((srow ^ (srow >> 2)) & 3))] = pack8(f);
      }
    }
#pragma unroll
    for (int cc = 0; cc < 2; ++cc) {
      int c = sc0 + cc;
      const float* p = Bw + (size_t)(n0 + srow) * K + kt + c * 8;
      float4 v0 = *(const float4*)p;
      float4 v1 = *(const float4*)(p + 4);
      float f[8] = {v0.x, v0.y, v0.z, v0.w, v1.x, v1.y, v1.z, v1.w};
      Bs[srow * 4 + (c ^ ((srow ^ (srow >> 2)) & 3))] = pack8(f);
    }
    __syncthreads();

    bf8 a[4], b[4];
#pragma unroll
    for (int i = 0; i < 4; ++i) {
      int ra = wr * 64 + i * 16 + lr;
      a[i] = __builtin_bit_cast(bf8, As[ra * 4 + (lq ^ ((ra ^ (ra >> 2)) & 3))]);
      int rb = wc * 64 + i * 16 + lr;
      b[i] = __builtin_bit_cast(bf8, Bs[rb * 4 + (lq ^ ((rb ^ (rb >> 2)) & 3))]);
    }
#pragma unroll
    for (int i = 0; i < 4; ++i)
#pragma unroll
      for (int j = 0; j < 4; ++j)
        acc[i][j] = __builtin_amdgcn_mfma_f32_16x16x32_bf16(a[i], b[j], acc[i][j], 0, 0, 0);
    __syncthreads();
  }

  if (TRANS) {
    float* C = (float*)Cv;
#pragma unroll
    for (int i = 0; i < 4; ++i)
#pragma unroll
      for (int j = 0; j < 4; ++j)
#pragma unroll
        for (int r = 0; r < 4; ++r) {
          int m = m0 + wr * 64 + i * 16 + lq * 4 + r;
          int n = n0 + wc * 64 + j * 16 + lr;
          C[(size_t)(m & 63) * (TT * NOUT) + (size_t)(m >> 6) * NOUT + n] = acc[i][j][r];
        }
  } else {
    unsigned short* C = (unsigned short*)Cv;
#pragma unroll
    for (int i = 0; i < 4; ++i)
#pragma unroll
      for (int j = 0; j < 4; ++j)
#pragma unroll
        for (int r = 0; r < 4; ++r) {
          int m = m0 + wr * 64 + i * 16 + lq * 4 + r;
          int n = n0 + wc * 64 + j * 16 + lr;
          C[sl_idx(m, n)] = f2bf(acc[i][j][r]);
        }
  }
}

// ---------------- persistent recurrence kernel (fence-free flag-flow) ------------
// 256 blocks: blockIdx.x = bh*128 + jb. Block produces slice (rows bh*32..+32, cols
// jb*16..+16). 16 waves = bg(2) x kg(8). Partials -> double-buffered red LDS; waves 0/1
// each reduce + store their own 16-row half (write-through), drain, publish sub-flag
// flags[block*2+bg]. Consumers poll sub-flags then pull h with 8x CACHEABLE dwordx4
// (L2-shared within the XCD). P-prefetch is a BYPASS atomic load (never cache-fills
// pre-write hseq addresses -- the no-fence safety invariant).
__global__ __launch_bounds__(1024, 4) void rnn_recur(unsigned short* __restrict__ hseq,
                                                     const float* __restrict__ Whh,
                                                     unsigned* __restrict__ flags) {
  __shared__ u4 Wl[16 * 256];          // 64 KiB: [j_local][k-chunk of 8], chunk ^ (j&7)
  __shared__ float red[2][8][32][20];  // 40 KiB: [buf][kg][local row][j 16 pad 20]
  const int t = threadIdx.x;
  const int jb = (int)blockIdx.x & 127;
  const int bh = (int)blockIdx.x >> 7;
  const int j0 = jb * 16;

  // one-time: W_hh j-slice -> swizzled LDS
  {
    const int jl = t >> 6;
    const int c0 = (t & 63) * 4;
#pragma unroll
    for (int c = 0; c < 4; ++c) {
      int cc = c0 + c;
      const float* p = Whh + (size_t)(j0 + jl) * NH + cc * 8;
      float4 v0 = *(const float4*)p;
      float4 v1 = *(const float4*)(p + 4);
      float f[8] = {v0.x, v0.y, v0.z, v0.w, v1.x, v1.y, v1.z, v1.w};
      Wl[jl * 256 + (cc ^ (jl & 7))] = pack8(f);
    }
  }

  const int l = t & 63, w = t >> 6;
  const int lr = l & 15, lq = l >> 4;
  const int bg = w & 1, kg = w >> 1;
  const int row = bh * 32 + bg * 16 + lr;

  // writer-wave lane roles (waves 0/1): 64 lanes = 16 local rows x 4 j-quarters (4 elems)
  const int wrowL = bg * 16 + (l >> 2);  // local row 0..31 (w<2 => bg==w)
  const int wjq = l & 3;
  const size_t woff = (size_t)(bh * 32 + wrowL) * 16 + wjq * 4;

  unsigned long long pre = 0;  // next-step P (4 bf16), writer waves only

  __syncthreads();  // Wl ready

  if (w < 2) {
    // h_0 = relu(P_0) (sign-bit relu exact in bf16), write-through; flag=1; prefetch P_1
    size_t e0 = ((size_t)jb << 10) + woff;
    unsigned long long p0 = *(const unsigned long long*)(hseq + e0);
    unsigned long long hv = 0;
#pragma unroll
    for (int i = 0; i < 4; ++i) {
      unsigned long long x = (p0 >> (16 * i)) & 0xffffull;
      if (!(x & 0x8000ull)) hv |= x << (16 * i);
    }
    __hip_atomic_store((unsigned long long*)(hseq + e0), hv, __ATOMIC_RELAXED,
                       __HIP_MEMORY_SCOPE_AGENT);
    asm volatile("s_waitcnt vmcnt(0)" ::: "memory");
    if (l == 0)
      __hip_atomic_store(flags + ((int)blockIdx.x * 2 + w), 1u, __ATOMIC_RELAXED,
                         __HIP_MEMORY_SCOPE_AGENT);
    // bypass prefetch of P_1 (must NOT fill L1/L2 -- pre-write address)
    pre = __hip_atomic_load(
        (const unsigned long long*)(hseq + (((size_t)128 + jb) << 10) + woff),
        __ATOMIC_RELAXED, __HIP_MEMORY_SCOPE_AGENT);
  }

  for (int ts = 1; ts < TT; ++ts) {
    // wait for the 16 producer sub-slices (own bg) covering this wave's k-eighth
    {
      const unsigned* fp = flags + ((bh * 128 + kg * 16 + lr) * 2 + bg);
      long spins = 0;
      for (;;) {
        unsigned fv = __hip_atomic_load(fp, __ATOMIC_RELAXED, __HIP_MEMORY_SCOPE_AGENT);
        if (__ballot(fv >= (unsigned)ts) == ~0ull) break;
        __builtin_amdgcn_s_sleep(1);
        if (++spins > (1L << 22)) break;  // hang safety
      }
    }
    asm volatile("" ::: "memory");  // keep data loads below the spin

    // a-frags: 8 x 16B CACHEABLE loads (fresh by flag protocol; L2-shared per XCD)
    const size_t tb = (size_t)(ts - 1) * 128;
    const size_t rowoff = (size_t)row * 16 + (lq & 1) * 8;
    const size_t sbase = tb + kg * 16 + (lq >> 1);
    unsigned long long ad[8];
#pragma unroll
    for (int u = 0; u < 8; ++u)
      ad[u] = (unsigned long long)(uintptr_t)(hseq + (((sbase + 2 * u) << 10) + rowoff));
    u4 av[8];
    asm volatile(
        "global_load_dwordx4 %0, %8, off\n\t"
        "global_load_dwordx4 %1, %9, off\n\t"
        "global_load_dwordx4 %2, %10, off\n\t"
        "global_load_dwordx4 %3, %11, off\n\t"
        "global_load_dwordx4 %4, %12, off\n\t"
        "global_load_dwordx4 %5, %13, off\n\t"
        "global_load_dwordx4 %6, %14, off\n\t"
        "global_load_dwordx4 %7, %15, off\n\t"
        "s_waitcnt vmcnt(0)"
        : "=&v"(av[0]), "=&v"(av[1]), "=&v"(av[2]), "=&v"(av[3]),
          "=&v"(av[4]), "=&v"(av[5]), "=&v"(av[6]), "=&v"(av[7])
        : "v"(ad[0]), "v"(ad[1]), "v"(ad[2]), "v"(ad[3]),
          "v"(ad[4]), "v"(ad[5]), "v"(ad[6]), "v"(ad[7])
        : "memory");

    f4 acc0 = {}, acc1 = {};
#pragma unroll
    for (int u = 0; u < 8; ++u) {
      bf8 af = __builtin_bit_cast(bf8, av[u]);
      int c = kg * 32 + u * 4 + lq;
      bf8 bfr = __builtin_bit_cast(bf8, Wl[lr * 256 + (c ^ (lr & 7))]);
      if (u & 1)
        acc1 = __builtin_amdgcn_mfma_f32_16x16x32_bf16(af, bfr, acc1, 0, 0, 0);
      else
        acc0 = __builtin_amdgcn_mfma_f32_16x16x32_bf16(af, bfr, acc0, 0, 0, 0);
    }
    f4 a2 = acc0 + acc1;

    const int buf = ts & 1;
#pragma unroll
    for (int r = 0; r < 4; ++r) red[buf][kg][bg * 16 + lq * 4 + r][lr] = a2[r];
    __syncthreads();

    if (w < 2) {
      f4 s = {};
#pragma unroll
      for (int q = 0; q < 8; ++q) s += *(const f4*)&red[buf][q][wrowL][wjq * 4];
      float sf[4];
#pragma unroll
      for (int i = 0; i < 4; ++i) {
        float v = s[i] + bf2f((unsigned short)((pre >> (16 * i)) & 0xffffull));
        sf[i] = v > 0.f ? v : 0.f;
      }
      unsigned lo = (unsigned)f2bf(sf[0]) | ((unsigned)f2bf(sf[1]) << 16);
      unsigned hi = (unsigned)f2bf(sf[2]) | ((unsigned)f2bf(sf[3]) << 16);
      unsigned long long hv = (unsigned long long)lo | ((unsigned long long)hi << 32);
      size_t eo = (((size_t)ts * 128 + jb) << 10) + woff;
      __hip_atomic_store((unsigned long long*)(hseq + eo), hv, __ATOMIC_RELAXED,
                         __HIP_MEMORY_SCOPE_AGENT);
      asm volatile("s_waitcnt vmcnt(0)" ::: "memory");  // same-wave drain: stores at LLC
      if (l == 0)
        __hip_atomic_store(flags + ((int)blockIdx.x * 2 + w), (unsigned)(ts + 1),
                           __ATOMIC_RELAXED, __HIP_MEMORY_SCOPE_AGENT);
      if (ts + 1 < TT)  // bypass prefetch (no cache fill of pre-write address)
        pre = __hip_atomic_load(
            (const unsigned long long*)(hseq + (((size_t)(ts + 1) * 128 + jb) << 10) + woff),
            __ATOMIC_RELAXED, __HIP_MEMORY_SCOPE_AGENT);
    }
  }
}

__global__ void kinit(unsigned* f) { f[threadIdx.x] = 0u; }

extern "C" void kernel_launch(void* const* d_in, const int* in_sizes, int n_in,
                              void* d_out, int out_size, void* d_ws, size_t ws_size,
                              hipStream_t stream) {
  const float* xs = (const float*)d_in[0];
  const float* Wih = (const float*)d_in[1];
  const float* Whh = (const float*)d_in[2];
  const float* Wout = (const float*)d_in[3];

  unsigned short* hseq = (unsigned short*)d_ws;  // sliced [TT][128][64][16] bf16 = 128 MiB
  unsigned* flags = (unsigned*)((char*)d_ws + (size_t)TT * BB * NH * 2);  // 512 x u32

  kinit<<<1, 512, 0, stream>>>(flags);

  // phase 1: P = xs @ W_ih^T -> bf16 sliced layout
  gemm_bt<false, false><<<(TT * BB / 128) * (NH / 128), 256, 0, stream>>>(
      (const void*)xs, Wih, (void*)hseq, TT * BB, NH, NIN);

  // phase 2: recurrence (fence-free flag-flow, cacheable h-reads)
  rnn_recur<<<256, 1024, 0, stream>>>(hseq, Whh, flags);

  // phase 3: out[b][t][o] = h_seq @ W_out^T
  gemm_bt<true, true><<<(TT * BB / 128) * (NOUT / 128), 256, 0, stream>>>(
      (const void*)hseq, Wout, d_out, TT * BB, NOUT, NH);
}

// Round 8
// 4081.049 us; speedup vs baseline: 2.7140x; 1.0175x over previous
//
#include <hip/hip_runtime.h>
#include <hip/hip_bf16.h>
#include <stdint.h>

// RNN: h_t = relu(xs_t @ W_ih^T + h_{t-1} @ W_hh^T); ys = (h_seq @ W_out^T) -> [B,T,O]
// R8: tag-in-data dataflow with BYPASS polling (R6's protocol, R5's load primitive).
//  - hseq holds ONLY h (bf16, sliced layout), memset-0 per call ("not ready": signs clear).
//  - Producers store h with every bf16 sign bit SET (h>=0, sign free) via write-through
//    sc0sc1 stores. No drain, no flags, no fences.
//  - Consumers RETRY 8x global_load_dwordx4 sc0 sc1 (LLC-direct, nothing cached, nothing
//    stale) until all sign bits set. Stale chunk = memset zeros -> detected with certainty.
//  - P = xs@Wih^T computed on the fly (4 MFMAs/wave from 32KB Wih LDS slice, xs
//    prefetched cacheable one step ahead). Phase-1 GEMM deleted; P never materialized.
//  - Phase 3 strips the tag bits off A.

#define TT 512
#define BB 64
#define NIN 1024
#define NH 2048
#define NOUT 1024

typedef __attribute__((ext_vector_type(8))) short bf8;
typedef __attribute__((ext_vector_type(4))) float f4;
typedef __attribute__((ext_vector_type(4))) unsigned int u4;

static __device__ __forceinline__ unsigned short f2bf(float f) {
  __hip_bfloat16 h = __float2bfloat16(f);
  return __builtin_bit_cast(unsigned short, h);
}
static __device__ __forceinline__ float bf2f(unsigned short v) {
  return __bfloat162float(__builtin_bit_cast(__hip_bfloat16, v));
}
static __device__ __forceinline__ u4 pack8(const float* f) {
  u4 r;
#pragma unroll
  for (int i = 0; i < 4; ++i) {
    unsigned lo = f2bf(f[2 * i]);
    unsigned hi = f2bf(f[2 * i + 1]);
    r[i] = lo | (hi << 16);
  }
  return r;
}

// sliced-layout element index for (m-row, k/j-col): h[t=m>>6][col>>4][m&63][col&15]
static __device__ __forceinline__ size_t sl_idx(int m, int col) {
  return (((size_t)(m >> 6) * 128 + (col >> 4)) << 10) + (size_t)(m & 63) * 16 + (col & 15);
}

// ---------------- generic C[M,N] = A[M,K] * B[N,K]^T (bf16 MFMA) ----------------
// ABF: A is bf16 in sliced layout with tag sign bits (masked off here). B is f32 weights.
// TRANS: store f32 out[b][t][n]; else store bf16 into sliced layout.
template <bool ABF, bool TRANS>
__global__ void gemm_bt(const void* __restrict__ Av, const float* __restrict__ Bw,
                        void* __restrict__ Cv, int M, int N, int K) {
  constexpr int BM = 128, BN = 128, BK = 32;
  __shared__ u4 As[BM * 4];
  __shared__ u4 Bs[BN * 4];
  const int nt = N / BN;
  const int mi = (int)blockIdx.x / nt;
  const int ni = (int)blockIdx.x % nt;
  const int m0 = mi * BM, n0 = ni * BN;
  const int t = threadIdx.x;
  const int l = t & 63, w = t >> 6, wr = w >> 1, wc = w & 1;
  const int lr = l & 15, lq = l >> 4;

  f4 acc[4][4] = {};

  const int srow = t >> 1;
  const int sc0 = (t & 1) * 2;
  const u4 msk = {0x7fff7fffu, 0x7fff7fffu, 0x7fff7fffu, 0x7fff7fffu};

  for (int kt = 0; kt < K; kt += BK) {
    if (ABF) {
      const unsigned short* A = (const unsigned short*)Av;
#pragma unroll
      for (int cc = 0; cc < 2; ++cc) {
        int c = sc0 + cc;
        u4 v = *(const u4*)(A + sl_idx(m0 + srow, kt + c * 8));
        v &= msk;  // strip tag sign bits
        As[srow * 4 + (c ^ ((srow ^ (srow >> 2)) & 3))] = v;
      }
    } else {
      const float* A = (const float*)Av;
#pragma unroll
      for (int cc = 0; cc < 2; ++cc) {
        int c = sc0 + cc;
        const float* p = A + (size_t)(m0 + srow) * K + kt + c * 8;
        float4 v0 = *(const float4*)p;
        float4 v1 = *(const float4*)(p + 4);
        float f[8] = {v0.x, v0.y, v0.z, v0.w, v1.x, v1.y, v1.z, v1.w};
        As[srow * 4 + (c ^ ((srow ^ (srow >> 2)) & 3))] = pack8(f);
      }
    }
#pragma unroll
    for (int cc = 0; cc < 2; ++cc) {
      int c = sc0 + cc;
      const float* p = Bw + (size_t)(n0 + srow) * K + kt + c * 8;
      float4 v0 = *(const float4*)p;
      float4 v1 = *(const float4*)(p + 4);
      float f[8] = {v0.x, v0.y, v0.z, v0.w, v1.x, v1.y, v1.z, v1.w};
      Bs[srow * 4 + (c ^ ((srow ^ (srow >> 2)) & 3))] = pack8(f);
    }
    __syncthreads();

    bf8 a[4], b[4];
#pragma unroll
    for (int i = 0; i < 4; ++i) {
      int ra = wr * 64 + i * 16 + lr;
      a[i] = __builtin_bit_cast(bf8, As[ra * 4 + (lq ^ ((ra ^ (ra >> 2)) & 3))]);
      int rb = wc * 64 + i * 16 + lr;
      b[i] = __builtin_bit_cast(bf8, Bs[rb * 4 + (lq ^ ((rb ^ (rb >> 2)) & 3))]);
    }
#pragma unroll
    for (int i = 0; i < 4; ++i)
#pragma unroll
      for (int j = 0; j < 4; ++j)
        acc[i][j] = __builtin_amdgcn_mfma_f32_16x16x32_bf16(a[i], b[j], acc[i][j], 0, 0, 0);
    __syncthreads();
  }

  if (TRANS) {
    float* C = (float*)Cv;
#pragma unroll
    for (int i = 0; i < 4; ++i)
#pragma unroll
      for (int j = 0; j < 4; ++j)
#pragma unroll
        for (int r = 0; r < 4; ++r) {
          int m = m0 + wr * 64 + i * 16 + lq * 4 + r;
          int n = n0 + wc * 64 + j * 16 + lr;
          C[(size_t)(m & 63) * (TT * NOUT) + (size_t)(m >> 6) * NOUT + n] = acc[i][j][r];
        }
  } else {
    unsigned short* C = (unsigned short*)Cv;
#pragma unroll
    for (int i = 0; i < 4; ++i)
#pragma unroll
      for (int j = 0; j < 4; ++j)
#pragma unroll
        for (int r = 0; r < 4; ++r) {
          int m = m0 + wr * 64 + i * 16 + lq * 4 + r;
          int n = n0 + wc * 64 + j * 16 + lr;
          C[sl_idx(m, n)] = f2bf(acc[i][j][r]);
        }
  }
}

// ---------------- persistent fused recurrence kernel (tag-flow, bypass poll) -----
// 256 blocks: blockIdx.x = bh*128 + jb. Block produces h slice (rows bh*32..+32, cols
// jb*16..+16) each step. 16 waves = bg(2) x kg(8). Per wave per step: 4 Wih MFMAs over
// prefetched xs frags + 8 Whh MFMAs over retry-verified h_{t-1} frags (bypass loads).
// Partials -> red LDS; waves 0/1 reduce, relu, tag, single write-through store.
__global__ __launch_bounds__(1024, 4) void rnn_recur(unsigned short* __restrict__ hseq,
                                                     const float* __restrict__ xs,
                                                     const float* __restrict__ Whh,
                                                     const float* __restrict__ Wih) {
  __shared__ u4 Wlh[16 * 256];         // 64 KiB: Whh [j_local][k-chunk of 8], chunk ^ (j&7)
  __shared__ u4 Wli[16 * 128];         // 32 KiB: Wih same scheme (128 chunks)
  __shared__ float red[2][8][32][20];  // 40 KiB: [buf][kg][local row][j 16 pad 20]
  const int t = threadIdx.x;
  const int jb = (int)blockIdx.x & 127;
  const int bh = (int)blockIdx.x >> 7;
  const int j0 = jb * 16;

  // one-time: W_hh and W_ih j-slices -> swizzled LDS (f32 -> bf16)
  {
    const int jl = t >> 6;
    const int c0 = (t & 63) * 4;
#pragma unroll
    for (int c = 0; c < 4; ++c) {
      int cc = c0 + c;
      const float* p = Whh + (size_t)(j0 + jl) * NH + cc * 8;
      float4 v0 = *(const float4*)p;
      float4 v1 = *(const float4*)(p + 4);
      float f[8] = {v0.x, v0.y, v0.z, v0.w, v1.x, v1.y, v1.z, v1.w};
      Wlh[jl * 256 + (cc ^ (jl & 7))] = pack8(f);
    }
    const int i0 = (t & 63) * 2;
#pragma unroll
    for (int c = 0; c < 2; ++c) {
      int cc = i0 + c;
      const float* p = Wih + (size_t)(j0 + jl) * NIN + cc * 8;
      float4 v0 = *(const float4*)p;
      float4 v1 = *(const float4*)(p + 4);
      float f[8] = {v0.x, v0.y, v0.z, v0.w, v1.x, v1.y, v1.z, v1.w};
      Wli[jl * 128 + (cc ^ (jl & 7))] = pack8(f);
    }
  }

  const int l = t & 63, w = t >> 6;
  const int lr = l & 15, lq = l >> 4;
  const int bg = w & 1, kg = w >> 1;
  const int row = bh * 32 + bg * 16 + lr;  // b-row of this lane's A fragments

  // writer-wave lane roles (waves 0/1): 64 lanes = 16 local rows x 4 j-quarters
  const int wrowL = bg * 16 + (l >> 2);
  const int wjq = l & 3;
  const size_t woff = (size_t)(bh * 32 + wrowL) * 16 + wjq * 4;

  const u4 msk = {0x7fff7fffu, 0x7fff7fffu, 0x7fff7fffu, 0x7fff7fffu};

  // xs fragment prefetch (f32 -> bf16): k = kg*128 + lq*8 + u*32, u=0..3
  bf8 xf[4];
  auto load_xs = [&](int tt) {
    const float* xp = xs + ((size_t)tt * BB + row) * NIN + kg * 128 + lq * 8;
#pragma unroll
    for (int u = 0; u < 4; ++u) {
      float4 v0 = *(const float4*)(xp + u * 32);
      float4 v1 = *(const float4*)(xp + u * 32 + 4);
      float f[8] = {v0.x, v0.y, v0.z, v0.w, v1.x, v1.y, v1.z, v1.w};
      xf[u] = __builtin_bit_cast(bf8, pack8(f));
    }
  };
  load_xs(0);

  __syncthreads();  // LDS weights ready

  for (int ts = 0; ts < TT; ++ts) {
    f4 acc0 = {}, acc1 = {};

    // ---- P contribution: 4 MFMAs over prefetched xs frags ----
#pragma unroll
    for (int u = 0; u < 4; ++u) {
      int c = kg * 16 + u * 4 + lq;
      bf8 bfr = __builtin_bit_cast(bf8, Wli[lr * 128 + (c ^ (lr & 7))]);
      if (u & 1)
        acc1 = __builtin_amdgcn_mfma_f32_16x16x32_bf16(xf[u], bfr, acc1, 0, 0, 0);
      else
        acc0 = __builtin_amdgcn_mfma_f32_16x16x32_bf16(xf[u], bfr, acc0, 0, 0, 0);
    }

    // ---- recurrent contribution: bypass retry-verified loads of h_{ts-1} ----
    if (ts > 0) {
      const size_t tb = (size_t)(ts - 1) * 128;
      const size_t rowoff = (size_t)row * 16 + (lq & 1) * 8;
      const size_t sbase = tb + kg * 16 + (lq >> 1);
      unsigned long long ad[8];
#pragma unroll
      for (int u = 0; u < 8; ++u)
        ad[u] = (unsigned long long)(uintptr_t)(hseq + (((sbase + 2 * u) << 10) + rowoff));
      u4 av[8];
      long spins = 0;
      for (;;) {
        asm volatile(
            "global_load_dwordx4 %0, %8, off sc0 sc1\n\t"
            "global_load_dwordx4 %1, %9, off sc0 sc1\n\t"
            "global_load_dwordx4 %2, %10, off sc0 sc1\n\t"
            "global_load_dwordx4 %3, %11, off sc0 sc1\n\t"
            "global_load_dwordx4 %4, %12, off sc0 sc1\n\t"
            "global_load_dwordx4 %5, %13, off sc0 sc1\n\t"
            "global_load_dwordx4 %6, %14, off sc0 sc1\n\t"
            "global_load_dwordx4 %7, %15, off sc0 sc1\n\t"
            "s_waitcnt vmcnt(0)"
            : "=&v"(av[0]), "=&v"(av[1]), "=&v"(av[2]), "=&v"(av[3]),
              "=&v"(av[4]), "=&v"(av[5]), "=&v"(av[6]), "=&v"(av[7])
            : "v"(ad[0]), "v"(ad[1]), "v"(ad[2]), "v"(ad[3]),
              "v"(ad[4]), "v"(ad[5]), "v"(ad[6]), "v"(ad[7])
            : "memory");
        unsigned m = 0xffffffffu;
#pragma unroll
        for (int u = 0; u < 8; ++u)
#pragma unroll
          for (int d = 0; d < 4; ++d) m &= av[u][d];
        bool ok = (m & 0x80008000u) == 0x80008000u;  // all 64 sign bits set -> fresh h
        if (__ballot(ok) == ~0ull) break;
        __builtin_amdgcn_s_sleep(1);
        if (++spins > (1L << 20)) break;  // hang safety; never hit when logic is correct
      }
#pragma unroll
      for (int u = 0; u < 8; ++u) {
        u4 v = av[u] & msk;  // strip tag signs
        bf8 af = __builtin_bit_cast(bf8, v);
        int c = kg * 32 + u * 4 + lq;
        bf8 bfr = __builtin_bit_cast(bf8, Wlh[lr * 256 + (c ^ (lr & 7))]);
        if (u & 1)
          acc1 = __builtin_amdgcn_mfma_f32_16x16x32_bf16(af, bfr, acc1, 0, 0, 0);
        else
          acc0 = __builtin_amdgcn_mfma_f32_16x16x32_bf16(af, bfr, acc0, 0, 0, 0);
      }
    }

    // prefetch next xs (cacheable; xs is read-only input -- safe; off critical path)
    if (ts + 1 < TT) load_xs(ts + 1);

    f4 a2 = acc0 + acc1;
    const int buf = ts & 1;
#pragma unroll
    for (int r = 0; r < 4; ++r) red[buf][kg][bg * 16 + lq * 4 + r][lr] = a2[r];
    __syncthreads();

    if (w < 2) {
      f4 s = {};
#pragma unroll
      for (int q = 0; q < 8; ++q) s += *(const f4*)&red[buf][q][wrowL][wjq * 4];
      unsigned short h0 = (s[0] > 0.f) ? f2bf(s[0]) : (unsigned short)0;
      unsigned short h1 = (s[1] > 0.f) ? f2bf(s[1]) : (unsigned short)0;
      unsigned short h2 = (s[2] > 0.f) ? f2bf(s[2]) : (unsigned short)0;
      unsigned short h3 = (s[3] > 0.f) ? f2bf(s[3]) : (unsigned short)0;
      unsigned long long hv = (unsigned long long)h0 | ((unsigned long long)h1 << 16) |
                              ((unsigned long long)h2 << 32) | ((unsigned long long)h3 << 48);
      hv |= 0x8000800080008000ull;  // tag: sign bit of every bf16 set
      size_t eo = (((size_t)ts * 128 + jb) << 10) + woff;
      __hip_atomic_store((unsigned long long*)(hseq + eo), hv, __ATOMIC_RELAXED,
                         __HIP_MEMORY_SCOPE_AGENT);  // write-through; the store IS the flag
    }
  }
}

extern "C" void kernel_launch(void* const* d_in, const int* in_sizes, int n_in,
                              void* d_out, int out_size, void* d_ws, size_t ws_size,
                              hipStream_t stream) {
  const float* xs = (const float*)d_in[0];
  const float* Wih = (const float*)d_in[1];
  const float* Whh = (const float*)d_in[2];
  const float* Wout = (const float*)d_in[3];

  unsigned short* hseq = (unsigned short*)d_ws;  // sliced [TT][128][64][16] bf16 = 128 MiB

  // zero hseq: "not ready" state (sign bits clear). Required every call (tag protocol).
  hipMemsetAsync(d_ws, 0, (size_t)TT * BB * NH * 2, stream);

  // fused phase 1+2: recurrence with on-the-fly P (tag-flow, bypass polling)
  rnn_recur<<<256, 1024, 0, stream>>>(hseq, xs, Whh, Wih);

  // phase 3: out[b][t][o] = h_seq @ W_out^T (strips tag bits)
  gemm_bt<true, true><<<(TT * BB / 128) * (NOUT / 128), 256, 0, stream>>>(
      (const void*)hseq, Wout, d_out, TT * BB, NOUT, NH);
}

// Round 9
// 3946.169 us; speedup vs baseline: 2.8067x; 1.0342x over previous
//
#include <hip/hip_runtime.h>
#include <hip/hip_bf16.h>
#include <stdint.h>

// RNN: h_t = relu(xs_t @ W_ih^T + h_{t-1} @ W_hh^T); ys = (h_seq @ W_out^T) -> [B,T,O]
// R9: 4 independent recurrence chains (16 batch rows each) x 64 j-blocks (32 cols each).
//  - Straggler domain 128 -> 64 blocks; chains fully decoupled.
//  - Per-block exchange halved (64KB/step); chunk == producer slice (exact alignment).
//  - 16-deep bypass load MLP (4 bases + offset: immediates, one vmcnt(0)).
//  - 8 waves/block = 4 k-quarters x 2 j-halves; Whh slice 128KB LDS; red 18KB.
//  - Flags (proven R5 protocol): store h (write-through) -> vmcnt(0) -> flag. Writers
//    s_setprio(1). P precomputed by phase-1 GEMM (cheapest measured), prefetched bypass.
//  - hseq slice layout: [t][g 4][jb 64][r 16][j 32] bf16 (1KB slices).

#define TT 512
#define BB 64
#define NIN 1024
#define NH 2048
#define NOUT 1024

typedef __attribute__((ext_vector_type(8))) short bf8;
typedef __attribute__((ext_vector_type(4))) float f4;
typedef __attribute__((ext_vector_type(4))) unsigned int u4;

static __device__ __forceinline__ unsigned short f2bf(float f) {
  __hip_bfloat16 h = __float2bfloat16(f);
  return __builtin_bit_cast(unsigned short, h);
}
static __device__ __forceinline__ float bf2f(unsigned short v) {
  return __bfloat162float(__builtin_bit_cast(__hip_bfloat16, v));
}
static __device__ __forceinline__ u4 pack8(const float* f) {
  u4 r;
#pragma unroll
  for (int i = 0; i < 4; ++i) {
    unsigned lo = f2bf(f[2 * i]);
    unsigned hi = f2bf(f[2 * i + 1]);
    r[i] = lo | (hi << 16);
  }
  return r;
}

// sliced layout: (m = t*64+b, col) -> [t][g=b>>4][jb=col>>5][r=b&15][jl=col&31]
static __device__ __forceinline__ size_t sl_idx(int m, int col) {
  return ((((size_t)(m >> 6) * 4 + ((m & 63) >> 4)) * 64 + (col >> 5)) << 9) +
         (size_t)((m & 63) & 15) * 32 + (col & 31);
}

// ---------------- generic C[M,N] = A[M,K] * B[N,K]^T (bf16 MFMA) ----------------
template <bool ABF, bool TRANS>
__global__ void gemm_bt(const void* __restrict__ Av, const float* __restrict__ Bw,
                        void* __restrict__ Cv, int M, int N, int K) {
  constexpr int BM = 128, BN = 128, BK = 32;
  __shared__ u4 As[BM * 4];
  __shared__ u4 Bs[BN * 4];
  const int nt = N / BN;
  const int mi = (int)blockIdx.x / nt;
  const int ni = (int)blockIdx.x % nt;
  const int m0 = mi * BM, n0 = ni * BN;
  const int t = threadIdx.x;
  const int l = t & 63, w = t >> 6, wr = w >> 1, wc = w & 1;
  const int lr = l & 15, lq = l >> 4;

  f4 acc[4][4] = {};

  const int srow = t >> 1;
  const int sc0 = (t & 1) * 2;

  for (int kt = 0; kt < K; kt += BK) {
    if (ABF) {
      const unsigned short* A = (const unsigned short*)Av;
#pragma unroll
      for (int cc = 0; cc < 2; ++cc) {
        int c = sc0 + cc;
        u4 v = *(const u4*)(A + sl_idx(m0 + srow, kt + c * 8));
        As[srow * 4 + (c ^ ((srow ^ (srow >> 2)) & 3))] = v;
      }
    } else {
      const float* A = (const float*)Av;
#pragma unroll
      for (int cc = 0; cc < 2; ++cc) {
        int c = sc0 + cc;
        const float* p = A + (size_t)(m0 + srow) * K + kt + c * 8;
        float4 v0 = *(const float4*)p;
        float4 v1 = *(const float4*)(p + 4);
        float f[8] = {v0.x, v0.y, v0.z, v0.w, v1.x, v1.y, v1.z, v1.w};
        As[srow * 4 + (c ^ ((srow ^ (srow >> 2)) & 3))] = pack8(f);
      }
    }
#pragma unroll
    for (int cc = 0; cc < 2; ++cc) {
      int c = sc0 + cc;
      const float* p = Bw + (size_t)(n0 + srow) * K + kt + c * 8;
      float4 v0 = *(const float4*)p;
      float4 v1 = *(const float4*)(p + 4);
      float f[8] = {v0.x, v0.y, v0.z, v0.w, v1.x, v1.y, v1.z, v1.w};
      Bs[srow * 4 + (c ^ ((srow ^ (srow >> 2)) & 3))] = pack8(f);
    }
    __syncthreads();

    bf8 a[4], b[4];
#pragma unroll
    for (int i = 0; i < 4; ++i) {
      int ra = wr * 64 + i * 16 + lr;
      a[i] = __builtin_bit_cast(bf8, As[ra * 4 + (lq ^ ((ra ^ (ra >> 2)) & 3))]);
      int rb = wc * 64 + i * 16 + lr;
      b[i] = __builtin_bit_cast(bf8, Bs[rb * 4 + (lq ^ ((rb ^ (rb >> 2)) & 3))]);
    }
#pragma unroll
    for (int i = 0; i < 4; ++i)
#pragma unroll
      for (int j = 0; j < 4; ++j)
        acc[i][j] = __builtin_amdgcn_mfma_f32_16x16x32_bf16(a[i], b[j], acc[i][j], 0, 0, 0);
    __syncthreads();
  }

  if (TRANS) {
    float* C = (float*)Cv;
#pragma unroll
    for (int i = 0; i < 4; ++i)
#pragma unroll
      for (int j = 0; j < 4; ++j)
#pragma unroll
        for (int r = 0; r < 4; ++r) {
          int m = m0 + wr * 64 + i * 16 + lq * 4 + r;
          int n = n0 + wc * 64 + j * 16 + lr;
          C[(size_t)(m & 63) * (TT * NOUT) + (size_t)(m >> 6) * NOUT + n] = acc[i][j][r];
        }
  } else {
    unsigned short* C = (unsigned short*)Cv;
#pragma unroll
    for (int i = 0; i < 4; ++i)
#pragma unroll
      for (int j = 0; j < 4; ++j)
#pragma unroll
        for (int r = 0; r < 4; ++r) {
          int m = m0 + wr * 64 + i * 16 + lq * 4 + r;
          int n = n0 + wc * 64 + j * 16 + lr;
          C[sl_idx(m, n)] = f2bf(acc[i][j][r]);
        }
  }
}

// ---------------- persistent recurrence kernel (4 chains x 64 blocks) ------------
// block: g = (bid&7)>>1 (chain, rows g*16..+16, lives on XCDs {2g,2g+1}),
//        jb = (bid>>3)*2 + (bid&1) (j-cols jb*32..+32).
// 8 waves = kg(4, k-quarters of 512) x jh(2, j-halves of 16). Waves 0/1 (kg=0) are the
// writers for jh 0/1. Per step per wave: 16 chunk-loads (chunk c == producer kg*16+c's
// full 32-j slice) -> 16 MFMAs -> red LDS; sync; writers reduce 4kg + P, relu, store,
// drain, flag, then issue next-step P prefetch (bypass).
__global__ __launch_bounds__(512, 2) void rnn_recur(unsigned short* __restrict__ hseq,
                                                    const float* __restrict__ Whh,
                                                    unsigned* __restrict__ flags) {
  __shared__ u4 Wl[32 * 256];          // 128 KiB: [j_local 32][k-chunk 256], chunk ^ (j&7)
  __shared__ float red[2][4][16][36];  // 18 KiB: [buf][kg][row][j 32 pad 36]
  const int t = threadIdx.x;
  const int bid = (int)blockIdx.x;
  const int g = (bid & 7) >> 1;
  const int jb = ((bid >> 3) << 1) | (bid & 1);
  const int j0 = jb * 32;

  // one-time: W_hh j-slice (32 rows x 2048) -> swizzled LDS (f32 -> bf16)
  {
    const int jl = t >> 4;        // 0..31
    const int ci = t & 15;        // 16 threads per j-row
#pragma unroll
    for (int q = 0; q < 16; ++q) {
      int cc = ci * 16 + q;
      const float* p = Whh + (size_t)(j0 + jl) * NH + cc * 8;
      float4 v0 = *(const float4*)p;
      float4 v1 = *(const float4*)(p + 4);
      float f[8] = {v0.x, v0.y, v0.z, v0.w, v1.x, v1.y, v1.z, v1.w};
      Wl[jl * 256 + (cc ^ (jl & 7))] = pack8(f);
    }
  }

  const int l = t & 63, w = t >> 6;
  const int lr = l & 15, lq = l >> 4;
  const int kg = w >> 1, jh = w & 1;

  char* hb = (char*)hseq;
  // slice byte base for (ts, producer p): (((ts*4+g)*64+p) << 10)
  const size_t gofs = (size_t)g << 16;  // g*64 slices * 1024B

  // writer lane roles (waves 0/1, jh == w): 64 lanes = 16 rows x 4 j-quads
  const int wr_r = l >> 2;
  const int wjq = l & 3;
  const size_t wbyte = (size_t)wr_r * 64 + jh * 32 + wjq * 8;

  unsigned long long pre = 0;  // P for next step (4 bf16), writer waves only

  __syncthreads();  // Wl ready

  if (w < 2) {
    // h_0 = relu(P_0); write-through; drain; flag=1; prefetch P_1 (bypass)
    size_t e0 = (gofs + ((size_t)jb << 10)) + wbyte;
    unsigned long long p0 = __hip_atomic_load((const unsigned long long*)(hb + e0),
                                              __ATOMIC_RELAXED, __HIP_MEMORY_SCOPE_AGENT);
    unsigned long long hv = 0;
#pragma unroll
    for (int i = 0; i < 4; ++i) {
      unsigned long long x = (p0 >> (16 * i)) & 0xffffull;
      if (!(x & 0x8000ull)) hv |= x << (16 * i);
    }
    __hip_atomic_store((unsigned long long*)(hb + e0), hv, __ATOMIC_RELAXED,
                       __HIP_MEMORY_SCOPE_AGENT);
    asm volatile("s_waitcnt vmcnt(0)" ::: "memory");
    if (l == 0)
      __hip_atomic_store(flags + ((g * 64 + jb) * 2 + w), 1u, __ATOMIC_RELAXED,
                         __HIP_MEMORY_SCOPE_AGENT);
    pre = __hip_atomic_load(
        (const unsigned long long*)(hb + ((size_t)(1 * 4) << 16) + gofs + ((size_t)jb << 10) + wbyte),
        __ATOMIC_RELAXED, __HIP_MEMORY_SCOPE_AGENT);
  }

  for (int ts = 1; ts < TT; ++ts) {
    // poll the 32 producer-half flags covering this wave's k-quarter
    {
      const unsigned* fp = flags + ((g * 64 + kg * 16 + (l >> 1)) * 2 + (l & 1));
      long spins = 0;
      for (;;) {
        unsigned fv = (l < 32) ? __hip_atomic_load(fp, __ATOMIC_RELAXED,
                                                   __HIP_MEMORY_SCOPE_AGENT)
                               : 0xffffffffu;
        if (__ballot(fv >= (unsigned)ts) == ~0ull) break;
        __builtin_amdgcn_s_sleep(1);
        if (++spins > (1L << 22)) break;  // hang safety
      }
    }
    asm volatile("" ::: "memory");  // keep data loads below the spin

    // 16 chunk loads (bypass), 16-deep: 4 base addrs + offset:{0,1024,2048,3072}
    const size_t rowoff = (size_t)(l & 15) * 64 + (size_t)(l >> 4) * 16;
    const size_t base = (((size_t)(ts - 1) * 4) << 16) + gofs + ((size_t)(kg * 16) << 10) + rowoff;
    unsigned long long a0 = (unsigned long long)(uintptr_t)(hb + base);
    unsigned long long a1 = a0 + 4096;
    unsigned long long a2 = a0 + 8192;
    unsigned long long a3 = a0 + 12288;
    u4 av[16];
    asm volatile(
        "global_load_dwordx4 %0, %16, off sc0 sc1\n\t"
        "global_load_dwordx4 %1, %16, off offset:1024 sc0 sc1\n\t"
        "global_load_dwordx4 %2, %16, off offset:2048 sc0 sc1\n\t"
        "global_load_dwordx4 %3, %16, off offset:3072 sc0 sc1\n\t"
        "global_load_dwordx4 %4, %17, off sc0 sc1\n\t"
        "global_load_dwordx4 %5, %17, off offset:1024 sc0 sc1\n\t"
        "global_load_dwordx4 %6, %17, off offset:2048 sc0 sc1\n\t"
        "global_load_dwordx4 %7, %17, off offset:3072 sc0 sc1\n\t"
        "global_load_dwordx4 %8, %18, off sc0 sc1\n\t"
        "global_load_dwordx4 %9, %18, off offset:1024 sc0 sc1\n\t"
        "global_load_dwordx4 %10, %18, off offset:2048 sc0 sc1\n\t"
        "global_load_dwordx4 %11, %18, off offset:3072 sc0 sc1\n\t"
        "global_load_dwordx4 %12, %19, off sc0 sc1\n\t"
        "global_load_dwordx4 %13, %19, off offset:1024 sc0 sc1\n\t"
        "global_load_dwordx4 %14, %19, off offset:2048 sc0 sc1\n\t"
        "global_load_dwordx4 %15, %19, off offset:3072 sc0 sc1\n\t"
        "s_waitcnt vmcnt(0)"
        : "=&v"(av[0]), "=&v"(av[1]), "=&v"(av[2]), "=&v"(av[3]),
          "=&v"(av[4]), "=&v"(av[5]), "=&v"(av[6]), "=&v"(av[7]),
          "=&v"(av[8]), "=&v"(av[9]), "=&v"(av[10]), "=&v"(av[11]),
          "=&v"(av[12]), "=&v"(av[13]), "=&v"(av[14]), "=&v"(av[15])
        : "v"(a0), "v"(a1), "v"(a2), "v"(a3)
        : "memory");

    f4 acc0 = {}, acc1 = {};
#pragma unroll
    for (int c = 0; c < 16; ++c) {
      bf8 af = __builtin_bit_cast(bf8, av[c]);
      int ci = kg * 64 + c * 4 + lq;
      bf8 bfr = __builtin_bit_cast(bf8, Wl[(jh * 16 + lr) * 256 + (ci ^ (lr & 7))]);
      if (c & 1)
        acc1 = __builtin_amdgcn_mfma_f32_16x16x32_bf16(af, bfr, acc1, 0, 0, 0);
      else
        acc0 = __builtin_amdgcn_mfma_f32_16x16x32_bf16(af, bfr, acc0, 0, 0, 0);
    }
    f4 a2v = acc0 + acc1;

    const int buf = ts & 1;
#pragma unroll
    for (int i = 0; i < 4; ++i) red[buf][kg][(l >> 4) * 4 + i][jh * 16 + (l & 15)] = a2v[i];
    __syncthreads();

    if (w < 2) {
      __builtin_amdgcn_s_setprio(1);
      f4 s = {};
#pragma unroll
      for (int q = 0; q < 4; ++q) s += *(const f4*)&red[buf][q][wr_r][jh * 16 + wjq * 4];
      float sf[4];
#pragma unroll
      for (int i = 0; i < 4; ++i) {
        float v = s[i] + bf2f((unsigned short)((pre >> (16 * i)) & 0xffffull));
        sf[i] = v > 0.f ? v : 0.f;
      }
      unsigned lo = (unsigned)f2bf(sf[0]) | ((unsigned)f2bf(sf[1]) << 16);
      unsigned hi = (unsigned)f2bf(sf[2]) | ((unsigned)f2bf(sf[3]) << 16);
      unsigned long long hv = (unsigned long long)lo | ((unsigned long long)hi << 32);
      size_t eo = (((size_t)ts * 4) << 16) + gofs + ((size_t)jb << 10) + wbyte;
      __hip_atomic_store((unsigned long long*)(hb + eo), hv, __ATOMIC_RELAXED,
                         __HIP_MEMORY_SCOPE_AGENT);
      asm volatile("s_waitcnt vmcnt(0)" ::: "memory");  // h at LLC before flag
      if (l == 0)
        __hip_atomic_store(flags + ((g * 64 + jb) * 2 + w), (unsigned)(ts + 1),
                           __ATOMIC_RELAXED, __HIP_MEMORY_SCOPE_AGENT);
      if (ts + 1 < TT)  // issue P prefetch AFTER flag (completes under next poll)
        pre = __hip_atomic_load(
            (const unsigned long long*)(hb + (((size_t)(ts + 1) * 4) << 16) + gofs +
                                        ((size_t)jb << 10) + wbyte),
            __ATOMIC_RELAXED, __HIP_MEMORY_SCOPE_AGENT);
      __builtin_amdgcn_s_setprio(0);
    }
  }
}

__global__ void kinit(unsigned* f) { f[threadIdx.x] = 0u; }

extern "C" void kernel_launch(void* const* d_in, const int* in_sizes, int n_in,
                              void* d_out, int out_size, void* d_ws, size_t ws_size,
                              hipStream_t stream) {
  const float* xs = (const float*)d_in[0];
  const float* Wih = (const float*)d_in[1];
  const float* Whh = (const float*)d_in[2];
  const float* Wout = (const float*)d_in[3];

  unsigned short* hseq = (unsigned short*)d_ws;  // sliced [TT][4][64][16][32] bf16 = 128 MiB
  unsigned* flags = (unsigned*)((char*)d_ws + (size_t)TT * BB * NH * 2);  // 512 x u32

  kinit<<<1, 512, 0, stream>>>(flags);

  // phase 1: P = xs @ W_ih^T -> bf16 sliced layout
  gemm_bt<false, false><<<(TT * BB / 128) * (NH / 128), 256, 0, stream>>>(
      (const void*)xs, Wih, (void*)hseq, TT * BB, NH, NIN);

  // phase 2: recurrence (4 decoupled chains, flag-flow)
  rnn_recur<<<256, 512, 0, stream>>>(hseq, Whh, flags);

  // phase 3: out[b][t][o] = h_seq @ W_out^T
  gemm_bt<true, true><<<(TT * BB / 128) * (NOUT / 128), 256, 0, stream>>>(
      (const void*)hseq, Wout, d_out, TT * BB, NOUT, NH);
}